// Round 13
// baseline (266.447 us; speedup 1.0000x reference)
//
#include <hip/hip_runtime.h>
#include <cstdint>
#include <cstddef>

// ============================================================================
// CrossAttention: LN -> Q proj ; cross -> KV proj ; per-head softmax(QK^T/8)V
// + residual. f32 interface; internals: split-bf16 MFMA GEMMs (hi+lo, 3
// mfma/step => ~fp32 accuracy), bf16 MFMA flash attention (f32 accum).
// B=2, S=2048, D=1024, H=16, Dh=64.
// ============================================================================

typedef float  f32x4  __attribute__((ext_vector_type(4)));
typedef __bf16 bf16x8 __attribute__((ext_vector_type(8)));
typedef __bf16 bf16x4 __attribute__((ext_vector_type(4)));
typedef __bf16 bf16x2 __attribute__((ext_vector_type(2)));

#define MFMA16(a, b, c) __builtin_amdgcn_mfma_f32_16x16x32_bf16((a), (b), (c), 0, 0, 0)

__device__ __forceinline__ void gll16(const void* g, void* l) {
  __builtin_amdgcn_global_load_lds(
      (const __attribute__((address_space(1))) unsigned int*)g,
      (__attribute__((address_space(3))) unsigned int*)l, 16, 0, 0);
}

// returns {hi, lo} — by value (vector elements can't bind to references)
__device__ __forceinline__ bf16x2 split2(float x) {
  bf16x2 r;
  __bf16 hh = (__bf16)x;
  r[0] = hh;
  r[1] = (__bf16)(x - (float)hh);
  return r;
}

// ---------------------------------------------------------------------------
// Prep v2: latency-bound -> ILP-rich.
//  blocks [0,1024): LayerNorm, ONE WAVE PER ROW (4 rows/block). 4 float4
//    loads per lane (ILP), wave-local shfl reduce — no LDS, no barrier.
//  blocks [1024,2048): casts, grid-strided: exactly 7 float4 per thread.
// ---------------------------------------------------------------------------
__global__ __launch_bounds__(256) void prep_kernel(
    const float* __restrict__ x, const float* __restrict__ w, const float* __restrict__ b,
    __bf16* __restrict__ xh, __bf16* __restrict__ xl,
    const float* __restrict__ c,  __bf16* __restrict__ ch, __bf16* __restrict__ cl,
    const float* __restrict__ kw, __bf16* __restrict__ kh, __bf16* __restrict__ kl,
    const float* __restrict__ qw, __bf16* __restrict__ qh, __bf16* __restrict__ ql)
{
  const int tid = threadIdx.x;
  if (blockIdx.x < 1024) {
    // ---- LayerNorm: wave w of this block owns row blk*4+w ----
    const int wave = tid >> 6, lane = tid & 63;
    const int row = blockIdx.x * 4 + wave;
    const float* xr = x + (size_t)row * 1024;
    float4 v[4];
#pragma unroll
    for (int j = 0; j < 4; ++j)
      v[j] = *reinterpret_cast<const float4*>(xr + j * 256 + lane * 4);
    float s = 0.f, s2 = 0.f;
#pragma unroll
    for (int j = 0; j < 4; ++j) {
      s  += v[j].x + v[j].y + v[j].z + v[j].w;
      s2 += v[j].x * v[j].x + v[j].y * v[j].y + v[j].z * v[j].z + v[j].w * v[j].w;
    }
#pragma unroll
    for (int o = 1; o < 64; o <<= 1) { s += __shfl_xor(s, o, 64); s2 += __shfl_xor(s2, o, 64); }
    const float mu = s * (1.f / 1024.f);
    const float rs = rsqrtf(s2 * (1.f / 1024.f) - mu * mu + 1e-5f);
#pragma unroll
    for (int j = 0; j < 4; ++j) {
      const float4 wv = *reinterpret_cast<const float4*>(w + j * 256 + lane * 4);
      const float4 bv = *reinterpret_cast<const float4*>(b + j * 256 + lane * 4);
      float o4[4] = {(v[j].x - mu) * rs * wv.x + bv.x, (v[j].y - mu) * rs * wv.y + bv.y,
                     (v[j].z - mu) * rs * wv.z + bv.z, (v[j].w - mu) * rs * wv.w + bv.w};
      bf16x4 h, l;
#pragma unroll
      for (int i = 0; i < 4; ++i) { bf16x2 hl = split2(o4[i]); h[i] = hl[0]; l[i] = hl[1]; }
      *reinterpret_cast<bf16x4*>(xh + (size_t)row * 1024 + j * 256 + lane * 4) = h;
      *reinterpret_cast<bf16x4*>(xl + (size_t)row * 1024 + j * 256 + lane * 4) = l;
    }
  } else {
    // ---- casts (float4 units): cross [0,1048576), kvw [..,1572864), qw [..,1835008) ----
    size_t i4 = (size_t)(blockIdx.x - 1024) * 256 + tid;
#pragma unroll
    for (int it = 0; it < 7; ++it, i4 += 262144) {
      const float* src; __bf16 *dh, *dl; size_t off4;
      if (i4 < 1048576)      { src = c;  dh = ch; dl = cl; off4 = i4; }
      else if (i4 < 1572864) { src = kw; dh = kh; dl = kl; off4 = i4 - 1048576; }
      else                   { src = qw; dh = qh; dl = ql; off4 = i4 - 1572864; }
      const float4 v = reinterpret_cast<const float4*>(src)[off4];
      float o4[4] = {v.x, v.y, v.z, v.w};
      bf16x4 h, l;
#pragma unroll
      for (int j = 0; j < 4; ++j) { bf16x2 hl = split2(o4[j]); h[j] = hl[0]; l[j] = hl[1]; }
      reinterpret_cast<bf16x4*>(dh)[off4] = h;
      reinterpret_cast<bf16x4*>(dl)[off4] = l;
    }
  }
}

// ---------------------------------------------------------------------------
// Split-bf16 GEMM tile body (m97 2-phase structure). cscale folds the softmax
// scale into the q-projection epilogue (free).
// ---------------------------------------------------------------------------
__device__ __forceinline__ void gemm_tile(
    const __bf16* __restrict__ Ah, const __bf16* __restrict__ Al,
    const __bf16* __restrict__ Bh, const __bf16* __restrict__ Bl,
    __bf16* __restrict__ C, int N, int m0, int n0, char* ldsb, float cscale)
{
  constexpr int K = 1024;
  const int tid  = threadIdx.x;
  const int wave = tid >> 6, lane = tid & 63;
  const int g = lane >> 4, qm = lane & 15;
  const int wr = wave >> 1, wc = wave & 1;

  f32x4 acc[4][4] = {};

  const int rr = tid >> 2;
  const int cc = tid & 3;
  const int wb = wave * 1024;

  for (int k0 = 0; k0 < K; k0 += 32) {
    const size_t a0 = (size_t)(m0 + rr) * K + k0 + cc * 8;
    const size_t a1 = (size_t)(m0 + 64 + rr) * K + k0 + cc * 8;
    const size_t b0 = (size_t)(n0 + rr) * K + k0 + cc * 8;
    const size_t b1 = (size_t)(n0 + 64 + rr) * K + k0 + cc * 8;
    gll16(Ah + a0, ldsb + 0     + wb);
    gll16(Ah + a1, ldsb + 4096  + wb);
    gll16(Al + a0, ldsb + 8192  + wb);
    gll16(Al + a1, ldsb + 12288 + wb);
    gll16(Bh + b0, ldsb + 16384 + wb);
    gll16(Bh + b1, ldsb + 20480 + wb);
    gll16(Bl + b0, ldsb + 24576 + wb);
    gll16(Bl + b1, ldsb + 28672 + wb);
    __syncthreads();

    bf16x8 bhf[4], blf[4];
#pragma unroll
    for (int nt = 0; nt < 4; ++nt) {
      const int brow = wc * 64 + nt * 16 + qm;
      const char* bp = ldsb + 16384 + brow * 64 + g * 16;
      bhf[nt] = *reinterpret_cast<const bf16x8*>(bp);
      blf[nt] = *reinterpret_cast<const bf16x8*>(bp + 8192);
    }
#pragma unroll
    for (int mt = 0; mt < 4; ++mt) {
      const int arow = wr * 64 + mt * 16 + qm;
      const char* ap = ldsb + arow * 64 + g * 16;
      const bf16x8 ahf = *reinterpret_cast<const bf16x8*>(ap);
      const bf16x8 alf = *reinterpret_cast<const bf16x8*>(ap + 8192);
#pragma unroll
      for (int nt = 0; nt < 4; ++nt) {
        acc[mt][nt] = MFMA16(ahf, bhf[nt], acc[mt][nt]);
        acc[mt][nt] = MFMA16(ahf, blf[nt], acc[mt][nt]);
        acc[mt][nt] = MFMA16(alf, bhf[nt], acc[mt][nt]);
      }
    }
    __syncthreads();
  }

#pragma unroll
  for (int mt = 0; mt < 4; ++mt)
#pragma unroll
    for (int nt = 0; nt < 4; ++nt) {
      const int col = n0 + wc * 64 + nt * 16 + qm;
#pragma unroll
      for (int r = 0; r < 4; ++r) {
        const int row = m0 + wr * 64 + mt * 16 + g * 4 + r;
        C[(size_t)row * N + col] = (__bf16)(acc[mt][nt][r] * cscale);
      }
    }
}

#define QSCALE (0.125f * 1.44269504f)   // (1/sqrt(64)) * log2(e), folded into q

__global__ __launch_bounds__(256) void gemm2_kernel(
    const __bf16* __restrict__ cAh, const __bf16* __restrict__ cAl,
    const __bf16* __restrict__ kWh, const __bf16* __restrict__ kWl, __bf16* __restrict__ kvC,
    const __bf16* __restrict__ xAh, const __bf16* __restrict__ xAl,
    const __bf16* __restrict__ qWh, const __bf16* __restrict__ qWl, __bf16* __restrict__ qC)
{
  __shared__ __bf16 lds[4 * 128 * 32];
  int t = blockIdx.x;
  if (t < 512)
    gemm_tile(cAh, cAl, kWh, kWl, kvC, 2048, (t >> 4) * 128, (t & 15) * 128, (char*)lds, 1.0f);
  else {
    t -= 512;
    gemm_tile(xAh, xAl, qWh, qWl, qC, 1024, (t >> 3) * 128, (t & 7) * 128, (char*)lds, QSCALE);
  }
}

__global__ __launch_bounds__(256) void gemm1_kernel(
    const __bf16* __restrict__ Ah, const __bf16* __restrict__ Al,
    const __bf16* __restrict__ Bh, const __bf16* __restrict__ Bl,
    __bf16* __restrict__ C, int N, float cscale)
{
  __shared__ __bf16 lds[4 * 128 * 32];
  gemm_tile(Ah, Al, Bh, Bl, C, N, blockIdx.y * 128, blockIdx.x * 128, (char*)lds, cscale);
}

// ---------------------------------------------------------------------------
// Flash attention + residual:
//   * q arrives PRE-SCALED by 0.125*log2e (folded into q-GEMM epilogue):
//     p = exp2(s) directly — kills 16 v_mul/iter.
//   * Pl stride reverted 80 -> 72 el (measured: stride-80 quadrupled
//     SQ_LDS_BANK_CONFLICT 1.05M->4.19M; stride-72 P-reads are 2-way=free).
// No-shift softmax + deferred denominator (validated round 9, absmax 0.031).
// 8 waves / QBLK=128, double-buffered K/Vt with prefetch.
// ---------------------------------------------------------------------------
__global__ __launch_bounds__(512) void attn_kernel(
    const __bf16* __restrict__ qb, const __bf16* __restrict__ kvb,
    const float* __restrict__ resid, float* __restrict__ out)
{
  const int bh = blockIdx.y, b = bh >> 4, h = bh & 15;
  const int q0 = blockIdx.x * 128;
  const int tid = threadIdx.x, wave = tid >> 6, lane = tid & 63;
  const int g = lane >> 4, qm = lane & 15;

  __shared__ __bf16 Kl[2][64 * 64];     // [buf][key][d], chunk-swizzled
  __shared__ __bf16 Vt[2][64 * 64];     // [buf][d][key], chunk-swizzled
  __shared__ __bf16 Pl[8][16 * 72];     // per-wave P transpose, stride 72 el

  // Q fragments: A-operand row = lane&15 = q, k-octet = lane>>4
  bf16x8 qf[2];
  {
    const size_t row = (size_t)(b * 2048 + q0 + wave * 16 + qm);
    const __bf16* p = qb + row * 1024 + h * 64 + g * 8;
    qf[0] = *reinterpret_cast<const bf16x8*>(p);
    qf[1] = *reinterpret_cast<const bf16x8*>(p + 32);
  }

  float lsum[4] = {0.f, 0.f, 0.f, 0.f};   // per-lane partial denominators
  f32x4 acco[4] = {};

  const int krow  = wave * 8 + (lane >> 3);
  const int kchnk = (lane & 7) ^ (krow & 7);
  const int vd0 = wave * 8;

  const size_t kv_base = (size_t)(b * 2048) * 2048 + h * 64;

  // ---- prologue: stage tile 0 ----
  gll16(kvb + kv_base + (size_t)krow * 2048 + kchnk * 8, (char*)Kl[0] + wave * 1024);
  bf16x8 vreg = *reinterpret_cast<const bf16x8*>(
      kvb + kv_base + (size_t)lane * 2048 + 1024 + vd0);
  {
#pragma unroll
    for (int j = 0; j < 8; ++j) {
      const int d = vd0 + j;
      const int ch = (lane >> 3) ^ (d & 7);
      Vt[0][d * 64 + ch * 8 + (lane & 7)] = vreg[j];
    }
  }
  __syncthreads();

  for (int t = 0; t < 32; ++t) {
    const int cur = t & 1, nxt = cur ^ 1;
    // ---- prefetch tile t+1 (targets nxt buffer; disjoint from cur) ----
    if (t < 31) {
      const size_t key0 = (size_t)(t + 1) * 64;
      gll16(kvb + kv_base + (key0 + krow) * 2048 + kchnk * 8,
            (char*)Kl[nxt] + wave * 1024);
      vreg = *reinterpret_cast<const bf16x8*>(
          kvb + kv_base + (key0 + lane) * 2048 + 1024 + vd0);
    }

    // ---- S = (q*scale2) K^T (lane holds S[q=g*4+r][key=kt*16+qm]) ----
    f32x4 s[4] = {};
    __builtin_amdgcn_s_setprio(1);
#pragma unroll
    for (int kt = 0; kt < 4; ++kt) {
      const int row = kt * 16 + qm;
#pragma unroll
      for (int kk = 0; kk < 2; ++kk) {
        const int ch = (kk * 4 + g) ^ (qm & 7);
        const bf16x8 kf = *reinterpret_cast<const bf16x8*>(&Kl[cur][row * 64 + ch * 8]);
        s[kt] = MFMA16(qf[kk], kf, s[kt]);
      }
    }
    __builtin_amdgcn_s_setprio(0);

    // ---- streaming softmax: p = exp2(s) directly (scale pre-folded) ----
#pragma unroll
    for (int r = 0; r < 4; ++r) {
#pragma unroll
      for (int kt = 0; kt < 4; ++kt) {
        const float p = exp2f(s[kt][r]);
        lsum[r] += p;
        Pl[wave][(g * 4 + r) * 72 + kt * 16 + qm] = (__bf16)p;
      }
    }

    // ---- O += P V ----
    __builtin_amdgcn_s_setprio(1);
#pragma unroll
    for (int ks = 0; ks < 2; ++ks) {
      const bf16x8 pf = *reinterpret_cast<const bf16x8*>(&Pl[wave][qm * 72 + ks * 32 + g * 8]);
#pragma unroll
      for (int dt = 0; dt < 4; ++dt) {
        const int drow = dt * 16 + qm;
        const int ch = (ks * 4 + g) ^ (qm & 7);
        const bf16x8 vf = *reinterpret_cast<const bf16x8*>(&Vt[cur][drow * 64 + ch * 8]);
        acco[dt] = MFMA16(pf, vf, acco[dt]);
      }
    }
    __builtin_amdgcn_s_setprio(0);

    // ---- land the prefetched V into Vt[nxt] ----
    if (t < 31) {
#pragma unroll
      for (int j = 0; j < 8; ++j) {
        const int d = vd0 + j;
        const int ch = (lane >> 3) ^ (d & 7);
        Vt[nxt][d * 64 + ch * 8 + (lane & 7)] = vreg[j];
      }
    }
    __syncthreads();
  }

  // ---- epilogue: one denominator reduce across the 16 key-lanes ----
#pragma unroll
  for (int r = 0; r < 4; ++r) {
#pragma unroll
    for (int o = 1; o < 16; o <<= 1) lsum[r] += __shfl_xor(lsum[r], o, 64);
  }
#pragma unroll
  for (int dt = 0; dt < 4; ++dt) {
    const int col = h * 64 + dt * 16 + qm;
#pragma unroll
    for (int r = 0; r < 4; ++r) {
      const size_t tok = (size_t)(b * 2048 + q0 + wave * 16 + g * 4 + r);
      out[tok * 1024 + col] = acco[dt][r] / lsum[r] + resid[tok * 1024 + col];
    }
  }
}

// ---------------------------------------------------------------------------
extern "C" void kernel_launch(void* const* d_in, const int* in_sizes, int n_in,
                              void* d_out, int out_size, void* d_ws, size_t ws_size,
                              hipStream_t stream)
{
  const float* inputs = (const float*)d_in[0];  // (2,2048,1024)
  const float* cross  = (const float*)d_in[1];  // (2,2048,1024)
  const float* lnw    = (const float*)d_in[2];  // (1024,)
  const float* lnb    = (const float*)d_in[3];  // (1024,)
  const float* kvw    = (const float*)d_in[4];  // (2048,1024)
  const float* qw     = (const float*)d_in[5];  // (1024,1024)
  float* out = (float*)d_out;

  char* ws = (char*)d_ws;
  const size_t MB = (size_t)1 << 20;
  __bf16* xh  = (__bf16*)(ws + 0 * MB);
  __bf16* xl  = (__bf16*)(ws + 8 * MB);
  __bf16* chh = (__bf16*)(ws + 16 * MB);
  __bf16* cll = (__bf16*)(ws + 24 * MB);
  __bf16* kwh = (__bf16*)(ws + 32 * MB);
  __bf16* kwl = (__bf16*)(ws + 36 * MB);
  __bf16* qwh = (__bf16*)(ws + 40 * MB);
  __bf16* qwl = (__bf16*)(ws + 42 * MB);
  __bf16* kvb = (__bf16*)(ws + 44 * MB);
  const bool merged = ws_size >= 68 * MB;
  __bf16* qbb = merged ? (__bf16*)(ws + 60 * MB) : (__bf16*)(ws + 16 * MB);

  prep_kernel<<<2048, 256, 0, stream>>>(inputs, lnw, lnb, xh, xl,
                                        cross, chh, cll, kvw, kwh, kwl, qw, qwh, qwl);
  if (merged) {
    gemm2_kernel<<<768, 256, 0, stream>>>(chh, cll, kwh, kwl, kvb,
                                          xh, xl, qwh, qwl, qbb);
  } else {
    gemm1_kernel<<<dim3(16, 32), 256, 0, stream>>>(chh, cll, kwh, kwl, kvb, 2048, 1.0f);
    gemm1_kernel<<<dim3(8, 32), 256, 0, stream>>>(xh, xl, qwh, qwl, qbb, 1024, QSCALE);
  }
  attn_kernel<<<dim3(16, 32), 512, 0, stream>>>(qbb, kvb, inputs, out);
}